// Round 11
// baseline (735.911 us; speedup 1.0000x reference)
//
#include <hip/hip_runtime.h>
#include <stdint.h>

#define NN    6000
#define KNNC  10
#define MM    (NN * 2 * (KNNC + 1))   // 132000
#define DD    (2 * NN)                // 12000
#define BLK   256

#define MLP_BLOCKS 512                       // 2048 waves
#define NWAVES     (MLP_BLOCKS * 4)
#define NGRP       (MM / 4)                  // 33000 groups of 4 rows (exact)

#define CAP     96                           // bucket capacity (mean 22)
#define OVF_IDX 8064
#define MAX_OVF 4096
#define BUCKET_OFF  32768
#define OVF_OFF     (BUCKET_OFF + 6000 * CAP * 16)

// lane-broadcast: VALU readlane -> SGPR (no memory pipe)
__device__ __forceinline__ float rlane(float v, int l) {
    return __builtin_bit_cast(float,
        __builtin_amdgcn_readlane(__builtin_bit_cast(int, v), l));
}

// ---------------- kernel 1: MLP (register weights) + bucket push -----------
// lane = neuron j; lane j holds weight columns W_l[k][j] in 192 VGPRs.
// __launch_bounds__(256,1): 512-VGPR budget -> NO SPILL (R9 failed because
// (256,2)'s 256-cap spilled the weight array back to scratch = VMEM).
// Inner loop: v_readlane + v_fma only -> issues on per-SIMD VALU (1024 of
// them), not the per-CU LDS/TA pipes that throttled every prior variant.
__global__ __launch_bounds__(BLK, 1) void mlp_bucket(
    const float* __restrict__ CK,    // [MM,3]
    const float* __restrict__ Win,   // [3,64]
    const float* __restrict__ bin,   // [64]
    const float* __restrict__ Whid,  // [3,64,64]
    const float* __restrict__ bhid,  // [3,64]
    const float* __restrict__ Wout,  // [64,4]
    const float* __restrict__ bout,  // [4]
    const int*   __restrict__ coo,   // [2,MM]
    int*    __restrict__ cnt,        // [8192]
    float4* __restrict__ bucket,     // [6000*CAP]
    int4*   __restrict__ ovf)        // [MAX_OVF]
{
    const int tid  = threadIdx.x;
    const int lane = tid & 63;
    const int gwid = blockIdx.x * 4 + (tid >> 6);   // global wave id

    // one-time register-resident weight load (coalesced per k)
    float W0[64], W1[64], W2[64];
#pragma unroll
    for (int k = 0; k < 64; k++) W0[k] = Whid[k * 64 + lane];
#pragma unroll
    for (int k = 0; k < 64; k++) W1[k] = Whid[4096 + k * 64 + lane];
#pragma unroll
    for (int k = 0; k < 64; k++) W2[k] = Whid[8192 + k * 64 + lane];

    const float wi0 = Win[lane], wi1 = Win[64 + lane], wi2 = Win[128 + lane];
    const float b0  = bin[lane];
    const float bh0 = bhid[lane], bh1 = bhid[64 + lane], bh2 = bhid[128 + lane];
    const float4 wo = ((const float4*)Wout)[lane];
    const float wc0 = wo.x + wo.z;                  // collapsed over mi
    const float wc1 = wo.y + wo.w;
    const float bo0 = bout[0] + bout[2];            // uniform -> SGPR
    const float bo1 = bout[1] + bout[3];

#define HIDDEN(W, BH)                                                   \
    {                                                                   \
        float g0 = (BH), g1 = (BH), g2 = (BH), g3 = (BH);               \
        _Pragma("unroll")                                               \
        for (int k = 0; k < 64; k++) {                                  \
            g0 = fmaf(W[k], rlane(h0, k), g0);                          \
            g1 = fmaf(W[k], rlane(h1, k), g1);                          \
            g2 = fmaf(W[k], rlane(h2, k), g2);                          \
            g3 = fmaf(W[k], rlane(h3, k), g3);                          \
        }                                                               \
        h0 = fmaxf(g0, 0.f); h1 = fmaxf(g1, 0.f);                       \
        h2 = fmaxf(g2, 0.f); h3 = fmaxf(g3, 0.f);                       \
    }

    for (int grp = gwid; grp < NGRP; grp += NWAVES) {
        const int rowbase = grp * 4;

        // cooperative CK load for 4 rows (12 floats)
        float vck = 0.f;
        if (lane < 12) vck = CK[rowbase * 3 + lane];

        // input layer 3 -> 64
        float h0 = fmaxf(fmaf(rlane(vck, 2), wi2,
                         fmaf(rlane(vck, 1), wi1,
                         fmaf(rlane(vck, 0), wi0, b0))), 0.f);
        float h1 = fmaxf(fmaf(rlane(vck, 5), wi2,
                         fmaf(rlane(vck, 4), wi1,
                         fmaf(rlane(vck, 3), wi0, b0))), 0.f);
        float h2 = fmaxf(fmaf(rlane(vck, 8), wi2,
                         fmaf(rlane(vck, 7), wi1,
                         fmaf(rlane(vck, 6), wi0, b0))), 0.f);
        float h3 = fmaxf(fmaf(rlane(vck, 11), wi2,
                         fmaf(rlane(vck, 10), wi1,
                         fmaf(rlane(vck, 9), wi0, b0))), 0.f);

        // hidden layers: zero memory ops
        HIDDEN(W0, bh0)
        HIDDEN(W1, bh1)
        HIDDEN(W2, bh2)

        // output layer: per-lane partials, butterfly reduce
        float p00 = h0 * wc0, p01 = h0 * wc1;
        float p10 = h1 * wc0, p11 = h1 * wc1;
        float p20 = h2 * wc0, p21 = h2 * wc1;
        float p30 = h3 * wc0, p31 = h3 * wc1;
#pragma unroll
        for (int m = 32; m; m >>= 1) {
            p00 += __shfl_xor(p00, m, 64);  p01 += __shfl_xor(p01, m, 64);
            p10 += __shfl_xor(p10, m, 64);  p11 += __shfl_xor(p11, m, 64);
            p20 += __shfl_xor(p20, m, 64);  p21 += __shfl_xor(p21, m, 64);
            p30 += __shfl_xor(p30, m, 64);  p31 += __shfl_xor(p31, m, 64);
        }

        // lane r (r<4) buckets row rowbase+r
        if (lane < 4) {
            const float a0 = (lane == 0 ? p00 : lane == 1 ? p10 : lane == 2 ? p20 : p30) + bo0;
            const float a1 = (lane == 0 ? p01 : lane == 1 ? p11 : lane == 2 ? p21 : p31) + bo1;
            const int myrow = rowbase + lane;
            const int r  = coo[myrow];            // 0..5999 tile id
            const int c2 = coo[MM + myrow] * 2;
            const int slot = atomicAdd(&cnt[r], 1);
            if (slot < CAP) {
                bucket[r * CAP + slot] = make_float4(__int_as_float(c2), a0, a1, 0.f);
            } else {
                const int o = atomicAdd(&cnt[OVF_IDX], 1);
                if (o < MAX_OVF)
                    ovf[o] = make_int4(r, c2, __float_as_int(a0), __float_as_int(a1));
            }
        }
    }
#undef HIDDEN
}

// ---------------- kernel 2: fill + patch (block owns rows 2b,2b+1) ---------
__global__ __launch_bounds__(BLK) void fill_patch(
    const int*    __restrict__ cnt,
    const float4* __restrict__ bucket,
    float*        __restrict__ out)
{
    const int b = blockIdx.x;                       // 0..5999
    float* rowbase = out + (long long)b * 2 * DD;   // rows 2b, 2b+1
    float4* dst = (float4*)rowbase;                 // 6000 float4s
    const float4 z = make_float4(0.f, 0.f, 0.f, 0.f);
    for (int i = threadIdx.x; i < 6000; i += BLK) dst[i] = z;
    __syncthreads();

    const int n = min(cnt[b], CAP);
    for (int t = threadIdx.x; t < n; t += BLK) {
        float4 e = bucket[b * CAP + t];
        const int c2 = __float_as_int(e.x);
        atomicAdd(rowbase + c2, e.y);               // (2b,   c2)  L2-hot
        atomicAdd(rowbase + DD + c2 + 1, e.z);      // (2b+1, c2+1)
    }
}

// ---------------- kernel 3: overflow fixup (empty in practice) -------------
__global__ __launch_bounds__(BLK) void ovf_apply(
    const int*  __restrict__ cnt,
    const int4* __restrict__ ovf,
    float*      __restrict__ out)
{
    const int n = min(cnt[OVF_IDX], MAX_OVF);
    const int t = blockIdx.x * BLK + threadIdx.x;
    if (t >= n) return;
    int4 e = ovf[t];
    float* rowbase = out + (long long)e.x * 2 * DD;
    atomicAdd(rowbase + e.y, __int_as_float(e.z));
    atomicAdd(rowbase + DD + e.y + 1, __int_as_float(e.w));
}

extern "C" void kernel_launch(void* const* d_in, const int* in_sizes, int n_in,
                              void* d_out, int out_size, void* d_ws, size_t ws_size,
                              hipStream_t stream) {
    const float* CK   = (const float*)d_in[0];
    const float* Win  = (const float*)d_in[1];
    const float* bin  = (const float*)d_in[2];
    const float* Whid = (const float*)d_in[3];
    const float* bhid = (const float*)d_in[4];
    const float* Wout = (const float*)d_in[5];
    const float* bout = (const float*)d_in[6];
    const int* coo    = (const int*)d_in[7];
    float* out        = (float*)d_out;

    int*    cnt    = (int*)d_ws;
    float4* bucket = (float4*)((char*)d_ws + BUCKET_OFF);
    int4*   ovf    = (int4*)((char*)d_ws + OVF_OFF);

    hipMemsetAsync(cnt, 0, 32768, stream);
    mlp_bucket<<<MLP_BLOCKS, BLK, 0, stream>>>(
        CK, Win, bin, Whid, bhid, Wout, bout, coo, cnt, bucket, ovf);
    fill_patch<<<NN, BLK, 0, stream>>>(cnt, bucket, out);
    ovf_apply<<<(MAX_OVF + BLK - 1) / BLK, BLK, 0, stream>>>(cnt, ovf, out);
}